// Round 9
// baseline (1285.260 us; speedup 1.0000x reference)
//
#include <hip/hip_runtime.h>
#include <hip/hip_bf16.h>

// B=2048, D=256, H=266 (pad N->272, K->288), S=50. All f32 I/O; bf16 MFMA inside.
// PERSISTENT KERNEL v9 = v8 structure with verified f2b packing (no cvt_pk):
//   128 blocks x 512 threads; block b owns batch rows [16b,16b+16) forever.
//   Y1/Y2/xc in LDS (padded strides YS=276/XS=260). MFMA A-fragments built ON
//   THE FLY from Y(LDS)+AC (affine+relu+f2b) inside the GEMM loop — the LDS
//   staging pass and its __syncthreads are gone (As kept only for P1's
//   transpose of register-resident xc). Cross-block = BN stats + barrier words
//   (LLC atomics; batched dwordx2 sc0/sc1 reads). Two-level monotonic barrier
//   with per-leaf release. Batch register prefetch of next-phase weights/dW.

#define BATCH 2048
#define DD    256
#define HH    266
#define HP    272
#define SS    50
#define BN_EPS 1e-5f
#define SIG   0.3f
#define AS_STRIDE 296   // LDS A-tile row stride in bf16 elements
#define YS    276       // LDS Y-tile row stride in f32 (272+4: bank-spread)
#define XS    260       // LDS xc-tile row stride in f32 (256+4: bank-spread)

// f32 workspace offsets
#define V_OFF  1638400        // [2048]
#define S1_OFF 1640448        // 2 parity x 8 reps x 544
#define S2_OFF 1649152
#define S1V_OFF 1657856       // 8 x 544
#define S2V_OFF 1662208
#define SV_OFF  1666560       // 16
#define WQ_OFF  1666576       // bf16 region starts here (16B aligned)

// swizzled weight strides (ushort units)
#define W1S 69632   // 8kt*17nt*512
#define W2S 78336   // 9*17*512
#define W3S 73728   // 9*16*512
#define W1Q_OFF 0
#define W2Q_OFF 3481600
#define W3Q_OFF 7398400
#define WV1Q_OFF 11084800
#define WV2Q_OFF 11154432

// barrier state: u32[768] at f32 index BAR_OFF
#define BAR_OFF 7283200

typedef unsigned short ushort_t;
using short8 = __attribute__((ext_vector_type(8))) short;
using f32x4  = __attribute__((ext_vector_type(4))) float;
using f32x2  = __attribute__((ext_vector_type(2))) float;

__device__ __forceinline__ ushort_t f2b(float f) {   // f32 -> bf16 bits, RNE
    unsigned u = __float_as_uint(f);
    unsigned r = u + 0x7FFF + ((u >> 16) & 1);
    return (ushort_t)(r >> 16);
}
// A-fragment from LDS Y-row + affine-relu (8 consecutive cols k0..k0+7)
__device__ __forceinline__ short8 mk_af(const float* __restrict__ yp,
                                        const float* __restrict__ a0,
                                        const float* __restrict__ c0) {
    unsigned u[4];
    #pragma unroll
    for (int j = 0; j < 4; ++j) {
        float r0 = fmaxf(fmaf(a0[2*j],   yp[2*j],   c0[2*j]),   0.f);
        float r1 = fmaxf(fmaf(a0[2*j+1], yp[2*j+1], c0[2*j+1]), 0.f);
        u[j] = (unsigned)f2b(r0) | ((unsigned)f2b(r1) << 16);
    }
    union { unsigned q[4]; short8 s; } cv;
    cv.q[0]=u[0]; cv.q[1]=u[1]; cv.q[2]=u[2]; cv.q[3]=u[3];
    return cv.s;
}
// A-fragment from raw global row (8 consecutive f32)
__device__ __forceinline__ short8 mk_raw(const float* __restrict__ xp) {
    unsigned u[4];
    #pragma unroll
    for (int j = 0; j < 4; ++j)
        u[j] = (unsigned)f2b(xp[2*j]) | ((unsigned)f2b(xp[2*j+1]) << 16);
    union { unsigned q[4]; short8 s; } cv;
    cv.q[0]=u[0]; cv.q[1]=u[1]; cv.q[2]=u[2]; cv.q[3]=u[3];
    return cv.s;
}
__device__ __forceinline__ short8 zero8() {
    union { unsigned q[4]; short8 s; } cv;
    cv.q[0]=0; cv.q[1]=0; cv.q[2]=0; cv.q[3]=0;
    return cv.s;
}

// coherent scalar load (LLC, bypass L1/L2)
__device__ __forceinline__ float ld_coh(const float* p) {
    return __hip_atomic_load((const float*)p, __ATOMIC_RELAXED, __HIP_MEMORY_SCOPE_AGENT);
}
// coherent 8B load via asm (batched issue; caller does ONE s_waitcnt + sched_barrier)
__device__ __forceinline__ f32x2 ld2_coh(const float* p) {
    f32x2 v;
    asm volatile("global_load_dwordx2 %0, %1, off sc0 sc1" : "=v"(v) : "v"(p));
    return v;
}
// parallel-issue prefetch pair (no chaining; consume later in one asm)
__device__ __forceinline__ void pf2(const f32x4* q, int n, int tid,
                                    f32x4& r0, f32x4& r1) {
    int i0 = (tid < n) ? tid : 0;
    int i1 = (tid + 512 < n) ? (tid + 512) : 0;
    r0 = q[i0];
    r1 = q[i1];
}

// ---------------- weight swizzle: f32 [K][N] -> bf16 B-frag layout ----------------
__global__ __launch_bounds__(256) void k_conv(const float* __restrict__ src,
                                              ushort_t* __restrict__ dst,
                                              int K, int N, int KT, int NT,
                                              long total) {
    long t = (long)blockIdx.x * 256 + threadIdx.x;
    if (t >= total) return;
    int per = KT * NT * 512;
    int step = (int)(t / per);
    int e = (int)(t - (long)step * per);
    int kt = e / (NT * 512);
    int r = e - kt * NT * 512;
    int nt = r / 512;
    int r2 = r & 511;
    int lane = r2 >> 3;
    int j = r2 & 7;
    int k = kt * 32 + (lane >> 4) * 8 + j;
    int n = nt * 16 + (lane & 15);
    float v = (k < K && n < N) ? src[(size_t)step * K * N + (size_t)k * N + n] : 0.f;
    dst[t] = f2b(v);
}

// ---------------- barrier pre-init (ws is poisoned between iterations) ----
__global__ __launch_bounds__(256) void k_pre(float* __restrict__ ws) {
    unsigned* bar = (unsigned*)(ws + BAR_OFF);
    for (int i = threadIdx.x; i < 768; i += 256) atomicExch(bar + i, 0u);
}

// ---------------- grid barrier: two-level monotonic tree, per-leaf release ----
__device__ __forceinline__ void grid_bar(unsigned* bar, unsigned gen, int bid) {
    __syncthreads();
    if (threadIdx.x == 0) {
        const int lf = bid & 7;
        unsigned* leaf = bar + lf * 32;
        unsigned* root = bar + 256;
        unsigned* rel  = bar + 288 + lf * 32;
        bool done = false;
        unsigned a = __hip_atomic_fetch_add(leaf, 1u, __ATOMIC_RELAXED, __HIP_MEMORY_SCOPE_AGENT);
        if (a == gen * 16u + 15u) {
            unsigned r = __hip_atomic_fetch_add(root, 1u, __ATOMIC_RELAXED, __HIP_MEMORY_SCOPE_AGENT);
            if (r == gen * 8u + 7u) {
                #pragma unroll
                for (int l = 0; l < 8; ++l)
                    __hip_atomic_store(bar + 288 + l * 32, gen + 1u, __ATOMIC_RELAXED, __HIP_MEMORY_SCOPE_AGENT);
                done = true;
            }
        }
        if (!done) {
            while (__hip_atomic_load(rel, __ATOMIC_RELAXED, __HIP_MEMORY_SCOPE_AGENT) < gen + 1u)
                __builtin_amdgcn_s_sleep(1);
        }
        asm volatile("" ::: "memory");
    }
    __syncthreads();
}

// BN affine constants: batched coherent dwordx2 reads, ONE waitcnt round trip.
__device__ __forceinline__ void compute_ac_coh(const float* __restrict__ si,
                                               const float* __restrict__ g,
                                               const float* __restrict__ be,
                                               float (*AC)[HP]) {
    int t = threadIdx.x;
    if (t < 136) {
        f32x2 sv[8], qv[8];
        #pragma unroll
        for (int r = 0; r < 8; ++r) {
            sv[r] = ld2_coh(si + r * 544 + 2 * t);
            qv[r] = ld2_coh(si + r * 544 + 272 + 2 * t);
        }
        asm volatile("s_waitcnt vmcnt(0)" ::: "memory");
        __builtin_amdgcn_sched_barrier(0);
        f32x2 s = sv[0], q = qv[0];
        #pragma unroll
        for (int r = 1; r < 8; ++r) { s += sv[r]; q += qv[r]; }
        #pragma unroll
        for (int j = 0; j < 2; ++j) {
            int col = 2 * t + j;
            float a = 0.f, c = 0.f;
            if (col < HH) {
                float mu  = s[j] * (1.0f / 2048.0f);
                float var = q[j] * (1.0f / 2048.0f) - mu * mu;
                float rs  = rsqrtf(fmaxf(var, 0.0f) + BN_EPS);
                a = g[col] * rs;
                c = be[col] - mu * a;
            }
            AC[0][col] = a;
            AC[1][col] = c;
        }
    }
}

// ---------------- phase: [affine-relu] GEMM, NT=17, 16 rows, 8 waves ----------
// mode 0: A-fragments direct from global gsrc (K=KT*32 exact, no affine);
// mode 2: A-fragments direct from LDS lsrc (stride YS) with affine-relu.
__device__ __forceinline__ void dev_lin16(
    int bid, int mode, int KT,
    const float* __restrict__ gsrc, const float* __restrict__ lsrc,
    const float* __restrict__ stats_in, const float* __restrict__ g,
    const float* __restrict__ be,
    const ushort_t* __restrict__ Wq, const float* __restrict__ bias,
    float* __restrict__ ylds, float* __restrict__ stats_out,
    float* __restrict__ zero_ptr, float (*AC)[HP])
{
    const int tid  = threadIdx.x;
    const int lane = tid & 63;
    const int wv   = tid >> 6;
    const int quad = lane >> 4;
    const int l15  = lane & 15;
    const int row0 = bid * 16;

    if (zero_ptr != nullptr && tid < 34)
        atomicExch(zero_ptr + bid * 34 + tid, 0.0f);

    if (mode == 2) { compute_ac_coh(stats_in, g, be, AC); __syncthreads(); }

    const float* yrow = (mode == 2) ? (lsrc + l15 * YS)
                                    : (gsrc + (size_t)(row0 + l15) * DD);

    // tiles t = wv + 8*i (i<2 for all waves; i==2 only wv==0 -> t=16)
    f32x4 acc[3];
    #pragma unroll
    for (int i = 0; i < 3; ++i) acc[i] = (f32x4){0.f, 0.f, 0.f, 0.f};

    #pragma unroll 3
    for (int kt = 0; kt < KT; ++kt) {
        int k0 = kt * 32 + quad * 8;
        short8 af;
        if (mode == 0)       af = mk_raw(yrow + k0);
        else if (k0 < HP)    af = mk_af(yrow + k0, &AC[0][k0], &AC[1][k0]);
        else                 af = zero8();
        const ushort_t* wp = Wq + ((size_t)(kt * 17 + wv)) * 512 + lane * 8;
        #pragma unroll
        for (int i = 0; i < 3; ++i) {
            if (i < 2 || wv == 0) {
                short8 bf = *(const short8*)(wp + (size_t)i * 8 * 512);
                acc[i] = __builtin_amdgcn_mfma_f32_16x16x32_bf16(af, bf, acc[i], 0, 0, 0);
            }
        }
    }

    #pragma unroll
    for (int i = 0; i < 3; ++i) {
        if (i == 2 && wv != 0) continue;
        int t = wv + 8 * i;
        int col = t * 16 + l15;
        float bj = (col < HH) ? bias[col] : 0.f;
        float y0 = acc[i][0] + bj, y1 = acc[i][1] + bj;
        float y2 = acc[i][2] + bj, y3 = acc[i][3] + bj;
        ylds[(quad*4 + 0) * YS + col] = y0;
        ylds[(quad*4 + 1) * YS + col] = y1;
        ylds[(quad*4 + 2) * YS + col] = y2;
        ylds[(quad*4 + 3) * YS + col] = y3;
        float sp = y0 + y1 + y2 + y3;
        float sq = y0*y0 + y1*y1 + y2*y2 + y3*y3;
        sp += __shfl_xor(sp, 16); sp += __shfl_xor(sp, 32);
        sq += __shfl_xor(sq, 16); sq += __shfl_xor(sq, 32);
        if (quad == 0 && col < HH) {
            float* spp = stats_out + (bid & 7) * 544;
            atomicAdd(spp + col, sp);
            atomicAdd(spp + 272 + col, sq);
        }
    }
}

// ---------------- phase: P3 grad GEMM + v/xc update + P1(s+1) GEMM --------------
__device__ __forceinline__ void dev_fused16(
    int bid,
    const float* __restrict__ y2l, const float* __restrict__ stats_in,
    const float* __restrict__ g2, const float* __restrict__ be2,
    const ushort_t* __restrict__ W3q, const float* __restrict__ b3,
    const float* __restrict__ law, const float* __restrict__ dWs,
    const float* __restrict__ tg, int s, int doP1,
    float* __restrict__ xcl, float* __restrict__ vv, float* __restrict__ outv,
    const ushort_t* __restrict__ W1q, const float* __restrict__ b1n,
    float* __restrict__ y1l, float* __restrict__ stats_out,
    float* __restrict__ zero_ptr,
    ushort_t* __restrict__ As, float (*AC)[HP], float* __restrict__ red)
{
    const int tid  = threadIdx.x;
    const int lane = tid & 63;
    const int wv   = tid >> 6;
    const int quad = lane >> 4;
    const int l15  = lane & 15;
    const int row0 = bid * 16;
    const int col0 = wv * 16 + l15;
    const int col1 = (wv + 8) * 16 + l15;

    // early global loads (L2-warm from P2's prefetch): latency hides under
    // compute_ac + P3 GEMM
    float dwv[2][4], lawv[2], b3v[2];
    #pragma unroll
    for (int r = 0; r < 4; ++r) {
        int rowg = row0 + quad * 4 + r;
        dwv[0][r] = dWs[(size_t)rowg * DD + col0];
        dwv[1][r] = dWs[(size_t)rowg * DD + col1];
    }
    lawv[0] = law[col0]; lawv[1] = law[col1];
    b3v[0]  = b3[col0];  b3v[1]  = b3[col1];

    if (zero_ptr != nullptr && tid < 34)
        atomicExch(zero_ptr + bid * 34 + tid, 0.0f);

    compute_ac_coh(stats_in, g2, be2, AC);
    __syncthreads();

    // P3 GEMM: KT=9, NT=16, tiles t = wv, wv+8; A direct from Y2s+AC
    const float* yrow = y2l + l15 * YS;
    f32x4 acc[2];
    acc[0] = (f32x4){0.f,0.f,0.f,0.f};
    acc[1] = (f32x4){0.f,0.f,0.f,0.f};
    #pragma unroll 3
    for (int kt = 0; kt < 9; ++kt) {
        int k0 = kt * 32 + quad * 8;
        short8 af = (k0 < HP) ? mk_af(yrow + k0, &AC[0][k0], &AC[1][k0]) : zero8();
        const ushort_t* wp = W3q + ((size_t)(kt * 16 + wv)) * 512 + lane * 8;
        acc[0] = __builtin_amdgcn_mfma_f32_16x16x32_bf16(af, *(const short8*)(wp),           acc[0], 0, 0, 0);
        acc[1] = __builtin_amdgcn_mfma_f32_16x16x32_bf16(af, *(const short8*)(wp + 8 * 512), acc[1], 0, 0, 0);
    }

    // epilogue: grad, row partials
    const float h   = tg[s + 1] - tg[s];
    const float srt = SIG * sqrtf(h);
    float grad[2][4], xcv[2][4];
    float sxr[4], sgr[4], sgnr[4];
    #pragma unroll
    for (int i = 0; i < 2; ++i) {
        int col = (i == 0) ? col0 : col1;
        #pragma unroll
        for (int r = 0; r < 4; ++r) {
            int rl = quad * 4 + r;
            float gd = acc[i][r] + b3v[i];
            float xv = xcl[rl * XS + col];
            float dw = dwv[i][r];
            float d  = xv - lawv[i];
            grad[i][r] = gd; xcv[i][r] = xv;
            if (i == 0) {
                sxr[r]  = d * d;
                sgr[r]  = gd * gd;
                sgnr[r] = gd * dw;
            } else {
                sxr[r]  = fmaf(d, d, sxr[r]);
                sgr[r]  = fmaf(gd, gd, sgr[r]);
                sgnr[r] = fmaf(gd, dw, sgnr[r]);
            }
        }
    }
    #pragma unroll
    for (int off = 1; off < 16; off <<= 1) {
        #pragma unroll
        for (int r = 0; r < 4; ++r) {
            sxr[r]  += __shfl_xor(sxr[r],  off);
            sgr[r]  += __shfl_xor(sgr[r],  off);
            sgnr[r] += __shfl_xor(sgnr[r], off);
        }
    }
    if (l15 == 0) {
        #pragma unroll
        for (int r = 0; r < 4; ++r) {
            int rr = quad * 4 + r;
            red[(wv * 16 + rr) * 3 + 0] = sxr[r];
            red[(wv * 16 + rr) * 3 + 1] = sgr[r];
            red[(wv * 16 + rr) * 3 + 2] = sgnr[r];
        }
    }
    __syncthreads();   // red ready

    if (tid < 16) {
        float sx = 0.f, sg = 0.f, sgn = 0.f;
        #pragma unroll
        for (int w = 0; w < 8; ++w) {
            sx  += red[(w * 16 + tid) * 3 + 0];
            sg  += red[(w * 16 + tid) * 3 + 1];
            sgn += red[(w * 16 + tid) * 3 + 2];
        }
        int row = row0 + tid;
        float f  = 0.5f * (sx + sg);
        float vn = vv[row] - f * h + srt * sgn;
        vv[row] = vn;
        if (s == SS - 1) outv[row] = vn;
    }

    // xc update (LDS) + stage new A1 into As (bf16, transpose via LDS)
    #pragma unroll
    for (int i = 0; i < 2; ++i) {
        int col = (i == 0) ? col0 : col1;
        #pragma unroll
        for (int r = 0; r < 4; ++r) {
            int rl = quad * 4 + r;
            float xn = xcv[i][r] - grad[i][r] * h + srt * dwv[i][r];
            xcl[rl * XS + col] = xn;
            if (doP1) As[rl * AS_STRIDE + col] = f2b(xn);
        }
    }
    if (!doP1) return;
    __syncthreads();

    // P1(s+1) GEMM: KT=8, NT=17 (A from As — xc transpose)
    f32x4 acc2[3];
    #pragma unroll
    for (int i = 0; i < 3; ++i) acc2[i] = (f32x4){0.f, 0.f, 0.f, 0.f};
    #pragma unroll 4
    for (int kt = 0; kt < 8; ++kt) {
        short8 af = *(const short8*)(&As[l15 * AS_STRIDE + kt * 32 + quad * 8]);
        const ushort_t* wp = W1q + ((size_t)(kt * 17 + wv)) * 512 + lane * 8;
        #pragma unroll
        for (int i = 0; i < 3; ++i) {
            if (i < 2 || wv == 0) {
                short8 bf = *(const short8*)(wp + (size_t)i * 8 * 512);
                acc2[i] = __builtin_amdgcn_mfma_f32_16x16x32_bf16(af, bf, acc2[i], 0, 0, 0);
            }
        }
    }
    #pragma unroll
    for (int i = 0; i < 3; ++i) {
        if (i == 2 && wv != 0) continue;
        int t = wv + 8 * i;
        int col = t * 16 + l15;
        float bj = (col < HH) ? b1n[col] : 0.f;
        float y0 = acc2[i][0] + bj, y1 = acc2[i][1] + bj;
        float y2 = acc2[i][2] + bj, y3 = acc2[i][3] + bj;
        y1l[(quad*4 + 0) * YS + col] = y0;
        y1l[(quad*4 + 1) * YS + col] = y1;
        y1l[(quad*4 + 2) * YS + col] = y2;
        y1l[(quad*4 + 3) * YS + col] = y3;
        float sp = y0 + y1 + y2 + y3;
        float sq = y0*y0 + y1*y1 + y2*y2 + y3*y3;
        sp += __shfl_xor(sp, 16); sp += __shfl_xor(sp, 32);
        sq += __shfl_xor(sq, 16); sq += __shfl_xor(sq, 32);
        if (quad == 0 && col < HH) {
            float* spp = stats_out + (bid & 7) * 544;
            atomicAdd(spp + col, sp);
            atomicAdd(spp + 272 + col, sq);
        }
    }
}

// ---------------- v0 layer 3 (N=1), 16 rows/block, 32 lanes/row ---------------
__device__ __forceinline__ void dev_v0l3_16(
    int bid, const float* __restrict__ y2l, const float* __restrict__ stats_in,
    const float* __restrict__ gv, const float* __restrict__ bev,
    const float* __restrict__ wv3, const float* __restrict__ bv3,
    float* __restrict__ vout, float* __restrict__ sv,
    float (*AC)[HP], float* __restrict__ xtra)
{
    const int tid = threadIdx.x;
    compute_ac_coh(stats_in, gv, bev, AC);
    __syncthreads();

    const int r  = tid >> 5;        // 0..15 (32 lanes per row)
    const int ks = tid & 31;
    int k0 = ks * 9, k1 = k0 + 9;
    if (k1 > HH) k1 = HH;
    float acc = 0.0f;
    for (int k = k0; k < k1; ++k) {
        float y  = y2l[r * YS + k];
        float a2 = fmaxf(fmaf(AC[0][k], y, AC[1][k]), 0.0f);
        acc = fmaf(a2, wv3[k], acc);
    }
    #pragma unroll
    for (int off = 1; off < 32; off <<= 1) acc += __shfl_xor(acc, off);
    if (ks == 0) {
        float y = acc + bv3[0];
        vout[bid * 16 + r] = y;
        xtra[r] = y;
        xtra[16 + r] = y * y;
    }
    __syncthreads();
    if (tid == 0) {
        float s = 0.f, q = 0.f;
        #pragma unroll
        for (int i = 0; i < 16; ++i) { s += xtra[i]; q += xtra[16 + i]; }
        atomicAdd(sv, s);
        atomicAdd(sv + 1, q);
    }
}

__device__ __forceinline__ void dev_v0fin16(int bid, float* __restrict__ v,
                                            const float* __restrict__ sv,
                                            const float* __restrict__ gv3,
                                            const float* __restrict__ bev3) {
    if (threadIdx.x < 16) {
        float s0 = ld_coh(sv);
        float s1 = ld_coh(sv + 1);
        float mu  = s0 * (1.0f / 2048.0f);
        float var = s1 * (1.0f / 2048.0f) - mu * mu;
        float rs  = rsqrtf(fmaxf(var, 0.0f) + BN_EPS);
        int row = bid * 16 + threadIdx.x;
        float y = v[row];
        v[row] = fmaxf(gv3[0] * (y - mu) * rs + bev3[0], 0.0f);
    }
}

// ---------------- the persistent kernel ----------------
__global__ __launch_bounds__(512) void k_persist(
    const float* __restrict__ x, const float* __restrict__ dW,
    const float* __restrict__ law, const float* __restrict__ tg,
    const float* __restrict__ b1, const float* __restrict__ g1, const float* __restrict__ be1,
    const float* __restrict__ b2, const float* __restrict__ g2, const float* __restrict__ be2,
    const float* __restrict__ b3,
    const float* __restrict__ bv1, const float* __restrict__ gv1, const float* __restrict__ bev1,
    const float* __restrict__ bv2, const float* __restrict__ gv2, const float* __restrict__ bev2,
    const float* __restrict__ Wv3, const float* __restrict__ bv3,
    const float* __restrict__ gv3, const float* __restrict__ bev3,
    float* __restrict__ ws, float* __restrict__ out)
{
    __shared__ ushort_t As[16 * AS_STRIDE];   //  9472 B (P1 transpose only)
    __shared__ float AC[2][HP];               //  2176 B
    __shared__ float Y1s[16 * YS];            // 17664 B
    __shared__ float Y2s[16 * YS];            // 17664 B
    __shared__ float XCs[16 * XS];            // 16640 B
    __shared__ float XTRA[384];               //  1536 B   total 65152 B

    const int bid = blockIdx.x;
    const int tid = threadIdx.x;

    float* V   = ws + V_OFF;
    float* S1  = ws + S1_OFF;
    float* S2  = ws + S2_OFF;
    float* S1v = ws + S1V_OFF;
    float* S2v = ws + S2V_OFF;
    float* SV  = ws + SV_OFF;
    ushort_t* WQ = (ushort_t*)(ws + WQ_OFF);
    ushort_t* W1q  = WQ + W1Q_OFF;
    ushort_t* W2q  = WQ + W2Q_OFF;
    ushort_t* W3q  = WQ + W3Q_OFF;
    ushort_t* Wv1q = WQ + WV1Q_OFF;
    ushort_t* Wv2q = WQ + WV2Q_OFF;
    unsigned* bar  = (unsigned*)(ws + BAR_OFF);

    unsigned gen = 0;
    const int sl = (bid >> 3) & 15;   // weight-prefetch slice (16 per XCD group)

    // ph0: xc(LDS) = x rows; zero stat buffers (LLC RMW), spread across blocks.
    for (int i = tid; i < 16 * DD; i += 512) {
        int r = i >> 8, c = i & 255;
        XCs[r * XS + c] = x[(size_t)bid * 16 * DD + i];
    }
    {
        int z = bid * 205 + tid;
        int ze = (bid + 1) * 205; if (ze > 26128) ze = 26128;
        if (tid < 205 && z < ze) atomicExch(S1 + z, 0.0f);
    }
    grid_bar(bar, gen, bid); gen++;

    // ph1: v0 layer 1 (x @ Wv1) -> Y1s, stats -> S1v
    dev_lin16(bid, 0, 8, x, nullptr, nullptr, nullptr, nullptr,
              Wv1q, bv1, Y1s, S1v, nullptr, AC);
    grid_bar(bar, gen, bid); gen++;

    // ph2: v0 layer 2 (relu(bn(Y1)) @ Wv2) -> Y2s, stats -> S2v
    dev_lin16(bid, 2, 9, nullptr, Y1s, S1v, gv1, bev1,
              Wv2q, bv2, Y2s, S2v, nullptr, AC);
    grid_bar(bar, gen, bid); gen++;

    // ph3: v0 layer 3 (N=1) -> V, SV
    dev_v0l3_16(bid, Y2s, S2v, gv2, bev2, Wv3, bv3, V, SV, AC, XTRA);
    grid_bar(bar, gen, bid); gen++;

    // ph4: v0 final BN+relu on V + P1(0): x @ W1[0] -> Y1s, stats -> S1[0];
    //      batch-prefetch W2(0) slice
    dev_v0fin16(bid, V, SV, gv3, bev3);
    dev_lin16(bid, 0, 8, x, nullptr, nullptr, nullptr, nullptr,
              W1q, b1, Y1s, S1, nullptr, AC);
    {
        f32x4 p0, p1;
        pf2((const f32x4*)((const char*)W2q + (size_t)sl * 9792), 612, tid, p0, p1);
        asm volatile("" :: "v"(p0), "v"(p1));
    }
    grid_bar(bar, gen, bid); gen++;

    // main loop: 2 phases (2 barriers) per step
    for (int s = 0; s < SS; ++s) {
        int p = s & 1;
        // P2: relu(bn(Y1)) @ W2[s] -> Y2s, stats -> S2[p]; zero S1[1-p]
        dev_lin16(bid, 2, 9, nullptr, Y1s, S1 + p * 4352,
                  g1 + s * HH, be1 + s * HH,
                  W2q + (size_t)s * W2S, b2 + s * HH,
                  Y2s, S2 + p * 4352, S1 + (1 - p) * 4352, AC);
        // batch-prefetch F(s) inputs: own dW slice, W3(s)/W1(s+1) slices, law/b3
        {
            f32x4 d0, d1, w30, w31, w10, w11, lb;
            pf2((const f32x4*)(dW + (size_t)s * BATCH * DD + (size_t)bid * 16 * DD),
                1024, tid, d0, d1);
            pf2((const f32x4*)((const char*)(W3q + (size_t)s * W3S) + (size_t)sl * 9216),
                576, tid, w30, w31);
            int sn0 = (s + 1 < SS) ? s + 1 : s;
            pf2((const f32x4*)((const char*)(W1q + (size_t)sn0 * W1S) + (size_t)sl * 8704),
                544, tid, w10, w11);
            const f32x4* ql = (const f32x4*)(law + (size_t)s * DD);
            const f32x4* qb = (const f32x4*)(b3 + (size_t)s * DD);
            lb = (tid < 64) ? ql[tid] : ((tid < 128) ? qb[tid - 64] : ql[0]);
            asm volatile("" :: "v"(d0), "v"(d1), "v"(w30), "v"(w31),
                              "v"(w10), "v"(w11), "v"(lb));
        }
        grid_bar(bar, gen, bid); gen++;

        // F: P3 grad + v/xc update + P1(s+1) -> Y1s, stats -> S1[1-p]; zero S2[1-p]
        int sn = (s + 1 < SS) ? s + 1 : 0;   // dummy valid ptrs when doP1==0
        dev_fused16(bid, Y2s, S2 + p * 4352,
                    g2 + s * HH, be2 + s * HH,
                    W3q + (size_t)s * W3S, b3 + s * DD,
                    law + s * DD, dW + (size_t)s * BATCH * DD,
                    tg, s, (s < SS - 1) ? 1 : 0,
                    XCs, V, out,
                    W1q + (size_t)sn * W1S, b1 + sn * HH,
                    Y1s, S1 + ((s + 1) & 1) * 4352,
                    S2 + (1 - p) * 4352, As, AC, XTRA);
        // batch-prefetch W2(s+1) slice
        if (s + 1 < SS) {
            f32x4 p0, p1;
            pf2((const f32x4*)((const char*)(W2q + (size_t)(s + 1) * W2S) + (size_t)sl * 9792),
                612, tid, p0, p1);
            asm volatile("" :: "v"(p0), "v"(p1));
        }
        grid_bar(bar, gen, bid); gen++;
    }
}

extern "C" void kernel_launch(void* const* d_in, const int* in_sizes, int n_in,
                              void* d_out, int out_size, void* d_ws, size_t ws_size,
                              hipStream_t stream)
{
    (void)in_sizes; (void)n_in; (void)out_size; (void)ws_size;
    const float* x    = (const float*)d_in[0];
    const float* dW   = (const float*)d_in[1];
    const float* law  = (const float*)d_in[2];
    const float* tg   = (const float*)d_in[3];
    const float* W1   = (const float*)d_in[4];
    const float* b1   = (const float*)d_in[5];
    const float* g1   = (const float*)d_in[6];
    const float* be1  = (const float*)d_in[7];
    const float* W2   = (const float*)d_in[8];
    const float* b2   = (const float*)d_in[9];
    const float* g2   = (const float*)d_in[10];
    const float* be2  = (const float*)d_in[11];
    const float* W3   = (const float*)d_in[12];
    const float* b3   = (const float*)d_in[13];
    const float* Wv1  = (const float*)d_in[14];
    const float* bv1  = (const float*)d_in[15];
    const float* gv1  = (const float*)d_in[16];
    const float* bev1 = (const float*)d_in[17];
    const float* Wv2  = (const float*)d_in[18];
    const float* bv2  = (const float*)d_in[19];
    const float* gv2  = (const float*)d_in[20];
    const float* bev2 = (const float*)d_in[21];
    const float* Wv3  = (const float*)d_in[22];
    const float* bv3  = (const float*)d_in[23];
    const float* gv3  = (const float*)d_in[24];
    const float* bev3 = (const float*)d_in[25];

    float* ws = (float*)d_ws;
    ushort_t* WQ = (ushort_t*)(ws + WQ_OFF);
    ushort_t* W1q  = WQ + W1Q_OFF;
    ushort_t* W2q  = WQ + W2Q_OFF;
    ushort_t* W3q  = WQ + W3Q_OFF;
    ushort_t* Wv1q = WQ + WV1Q_OFF;
    ushort_t* Wv2q = WQ + WV2Q_OFF;
    float* out = (float*)d_out;

    k_pre<<<1, 256, 0, stream>>>(ws);
    k_conv<<<13600, 256, 0, stream>>>(W1,  W1q,  DD, HH, 8, 17, (long)SS * W1S);
    k_conv<<<15300, 256, 0, stream>>>(W2,  W2q,  HH, HH, 9, 17, (long)SS * W2S);
    k_conv<<<14400, 256, 0, stream>>>(W3,  W3q,  HH, DD, 9, 16, (long)SS * W3S);
    k_conv<<<272,   256, 0, stream>>>(Wv1, Wv1q, DD, HH, 8, 17, (long)W1S);
    k_conv<<<306,   256, 0, stream>>>(Wv2, Wv2q, HH, HH, 9, 17, (long)W2S);

    k_persist<<<128, 512, 0, stream>>>(
        x, dW, law, tg,
        b1, g1, be1, b2, g2, be2, b3,
        bv1, gv1, bev1, bv2, gv2, bev2,
        Wv3, bv3, gv3, bev3,
        ws, out);
}

// Round 10
// 1224.270 us; speedup vs baseline: 1.0498x; 1.0498x over previous
//
#include <hip/hip_runtime.h>
#include <hip/hip_bf16.h>

// B=2048, D=256, H=266 (pad N->272, K->288), S=50. All f32 I/O; bf16 MFMA inside.
// PERSISTENT KERNEL v10 = v7 k_persist (best measured: 1049us) + fast weight
// swizzle: templated k_conv_t<KT,NT> (constexpr divisors -> magic multiplies,
// int-only arithmetic, blockIdx.y=step, v0 weights folded in) -> 3 launches.

#define BATCH 2048
#define DD    256
#define HH    266
#define HP    272
#define SS    50
#define BN_EPS 1e-5f
#define SIG   0.3f
#define AS_STRIDE 296   // LDS A-tile row stride in bf16 elements
#define YS    276       // LDS Y-tile row stride in f32 (272+4: bank-spread)
#define XS    260       // LDS xc-tile row stride in f32 (256+4: bank-spread)

// f32 workspace offsets
#define V_OFF  1638400        // [2048]
#define S1_OFF 1640448        // 2 parity x 8 reps x 544
#define S2_OFF 1649152
#define S1V_OFF 1657856       // 8 x 544
#define S2V_OFF 1662208
#define SV_OFF  1666560       // 16
#define WQ_OFF  1666576       // bf16 region starts here (16B aligned)

// swizzled weight strides (ushort units)
#define W1S 69632   // 8kt*17nt*512
#define W2S 78336   // 9*17*512
#define W3S 73728   // 9*16*512
#define W1Q_OFF 0
#define W2Q_OFF 3481600
#define W3Q_OFF 7398400
#define WV1Q_OFF 11084800
#define WV2Q_OFF 11154432

// barrier state: u32[768] at f32 index BAR_OFF
#define BAR_OFF 7283200

typedef unsigned short ushort_t;
using short8 = __attribute__((ext_vector_type(8))) short;
using f32x4  = __attribute__((ext_vector_type(4))) float;
using f32x2  = __attribute__((ext_vector_type(2))) float;

__device__ __forceinline__ ushort_t f2b(float f) {   // f32 -> bf16 bits, RNE
    unsigned u = __float_as_uint(f);
    unsigned r = u + 0x7FFF + ((u >> 16) & 1);
    return (ushort_t)(r >> 16);
}

// coherent scalar load (LLC, bypass L1/L2)
__device__ __forceinline__ float ld_coh(const float* p) {
    return __hip_atomic_load((const float*)p, __ATOMIC_RELAXED, __HIP_MEMORY_SCOPE_AGENT);
}
// coherent 8B load via asm (batched issue; caller does ONE s_waitcnt + sched_barrier)
__device__ __forceinline__ f32x2 ld2_coh(const float* p) {
    f32x2 v;
    asm volatile("global_load_dwordx2 %0, %1, off sc0 sc1" : "=v"(v) : "v"(p));
    return v;
}
// parallel-issue prefetch pair (no chaining; consume later in one asm)
__device__ __forceinline__ void pf2(const f32x4* q, int n, int tid,
                                    f32x4& r0, f32x4& r1) {
    int i0 = (tid < n) ? tid : 0;
    int i1 = (tid + 512 < n) ? (tid + 512) : 0;
    r0 = q[i0];
    r1 = q[i1];
}

// ---------------- weight swizzle: f32 [K][N] -> bf16 B-frag layout ----------------
// Templated: KT/NT constexpr -> all div/mod become magic multiplies.
// Grid: (KT*NT*2, steps[+1]); blockIdx.y == nsteps handles the v0 weight (src2).
template<int KT, int NT>
__global__ __launch_bounds__(256) void k_conv_t(
    const float* __restrict__ src, ushort_t* __restrict__ dst,
    int K, int N, int nsteps,
    const float* __restrict__ src2, ushort_t* __restrict__ dst2,
    int K2, int N2)
{
    constexpr int PER = KT * NT * 512;
    const int step = blockIdx.y;
    const int e = blockIdx.x * 256 + threadIdx.x;   // < PER by grid construction
    const int tile = e >> 9;
    const int r2 = e & 511;
    const int kt = tile / NT;              // constexpr divisor
    const int nt = tile - kt * NT;
    const int lane = r2 >> 3;
    const int j = r2 & 7;
    const int k = kt * 32 + ((lane >> 4) << 3) + j;
    const int n = nt * 16 + (lane & 15);
    const float* s; ushort_t* d; int KK, NN;
    if (step < nsteps) {
        s = src + (size_t)step * K * N;
        d = dst + (size_t)step * PER;
        KK = K; NN = N;
    } else {
        s = src2; d = dst2; KK = K2; NN = N2;
    }
    float v = (k < KK && n < NN) ? s[(size_t)k * NN + n] : 0.f;
    d[e] = f2b(v);
}

// ---------------- barrier pre-init (ws is poisoned between iterations) ----
__global__ __launch_bounds__(256) void k_pre(float* __restrict__ ws) {
    unsigned* bar = (unsigned*)(ws + BAR_OFF);
    for (int i = threadIdx.x; i < 768; i += 256) atomicExch(bar + i, 0u);
}

// ---------------- grid barrier: two-level monotonic tree, per-leaf release ----
// 8 leaves x 16 arrivals (parallel across LLC lines); root 8; release fanned to
// 8 per-leaf words (<=16 pollers each). Monotonic -> no reset race.
__device__ __forceinline__ void grid_bar(unsigned* bar, unsigned gen, int bid) {
    __syncthreads();
    if (threadIdx.x == 0) {
        const int lf = bid & 7;
        unsigned* leaf = bar + lf * 32;
        unsigned* root = bar + 256;
        unsigned* rel  = bar + 288 + lf * 32;
        bool done = false;
        unsigned a = __hip_atomic_fetch_add(leaf, 1u, __ATOMIC_RELAXED, __HIP_MEMORY_SCOPE_AGENT);
        if (a == gen * 16u + 15u) {
            unsigned r = __hip_atomic_fetch_add(root, 1u, __ATOMIC_RELAXED, __HIP_MEMORY_SCOPE_AGENT);
            if (r == gen * 8u + 7u) {
                #pragma unroll
                for (int l = 0; l < 8; ++l)
                    __hip_atomic_store(bar + 288 + l * 32, gen + 1u, __ATOMIC_RELAXED, __HIP_MEMORY_SCOPE_AGENT);
                done = true;
            }
        }
        if (!done) {
            while (__hip_atomic_load(rel, __ATOMIC_RELAXED, __HIP_MEMORY_SCOPE_AGENT) < gen + 1u)
                __builtin_amdgcn_s_sleep(1);
        }
        asm volatile("" ::: "memory");
    }
    __syncthreads();
}

// BN affine constants: batched coherent dwordx2 reads, ONE waitcnt round trip.
__device__ __forceinline__ void compute_ac_coh(const float* __restrict__ si,
                                               const float* __restrict__ g,
                                               const float* __restrict__ be,
                                               float (*AC)[HP]) {
    int t = threadIdx.x;
    if (t < 136) {
        f32x2 sv[8], qv[8];
        #pragma unroll
        for (int r = 0; r < 8; ++r) {
            sv[r] = ld2_coh(si + r * 544 + 2 * t);
            qv[r] = ld2_coh(si + r * 544 + 272 + 2 * t);
        }
        asm volatile("s_waitcnt vmcnt(0)" ::: "memory");
        __builtin_amdgcn_sched_barrier(0);
        f32x2 s = sv[0], q = qv[0];
        #pragma unroll
        for (int r = 1; r < 8; ++r) { s += sv[r]; q += qv[r]; }
        #pragma unroll
        for (int j = 0; j < 2; ++j) {
            int col = 2 * t + j;
            float a = 0.f, c = 0.f;
            if (col < HH) {
                float mu  = s[j] * (1.0f / 2048.0f);
                float var = q[j] * (1.0f / 2048.0f) - mu * mu;
                float rs  = rsqrtf(fmaxf(var, 0.0f) + BN_EPS);
                a = g[col] * rs;
                c = be[col] - mu * a;
            }
            AC[0][col] = a;
            AC[1][col] = c;
        }
    }
}

// ---------------- phase: [affine-relu] GEMM, NT=17, 16 rows, 8 waves ----------
__device__ __forceinline__ void dev_lin16(
    int bid, int mode, int KT,
    const float* __restrict__ gsrc, const float* __restrict__ lsrc,
    const float* __restrict__ stats_in, const float* __restrict__ g,
    const float* __restrict__ be,
    const ushort_t* __restrict__ Wq, const float* __restrict__ bias,
    float* __restrict__ ylds, float* __restrict__ stats_out,
    float* __restrict__ zero_ptr,
    ushort_t* __restrict__ As, float (*AC)[HP])
{
    const int tid  = threadIdx.x;
    const int lane = tid & 63;
    const int wv   = tid >> 6;
    const int quad = lane >> 4;
    const int l15  = lane & 15;
    const int row0 = bid * 16;

    if (zero_ptr != nullptr && tid < 34)
        atomicExch(zero_ptr + bid * 34 + tid, 0.0f);

    if (mode == 2) { compute_ac_coh(stats_in, g, be, AC); __syncthreads(); }

    const int PAIRS = KT * 16;
    for (int idx = tid; idx < 16 * PAIRS; idx += 512) {
        int m  = idx / PAIRS;
        int kk = (idx - m * PAIRS) * 2;
        float v0, v1;
        if (mode == 2) {
            v0 = (kk < HH)   ? fmaxf(fmaf(AC[0][kk],   lsrc[m * YS + kk],   AC[1][kk]),   0.f) : 0.f;
            v1 = (kk+1 < HH) ? fmaxf(fmaf(AC[0][kk+1], lsrc[m * YS + kk+1], AC[1][kk+1]), 0.f) : 0.f;
        } else {
            v0 = gsrc[(size_t)(row0 + m) * DD + kk];
            v1 = gsrc[(size_t)(row0 + m) * DD + kk + 1];
        }
        ((unsigned int*)As)[m * (AS_STRIDE/2) + (kk >> 1)] =
            (unsigned int)f2b(v0) | ((unsigned int)f2b(v1) << 16);
    }
    __syncthreads();

    // tiles t = wv + 8*i (i<2 for all waves; i==2 only wv==0 -> t=16)
    f32x4 acc[3];
    #pragma unroll
    for (int i = 0; i < 3; ++i) acc[i] = (f32x4){0.f, 0.f, 0.f, 0.f};

    #pragma unroll 3
    for (int kt = 0; kt < KT; ++kt) {
        short8 af = *(const short8*)(&As[l15 * AS_STRIDE + kt * 32 + quad * 8]);
        const ushort_t* wp = Wq + ((size_t)(kt * 17 + wv)) * 512 + lane * 8;
        #pragma unroll
        for (int i = 0; i < 3; ++i) {
            if (i < 2 || wv == 0) {
                short8 bf = *(const short8*)(wp + (size_t)i * 8 * 512);
                acc[i] = __builtin_amdgcn_mfma_f32_16x16x32_bf16(af, bf, acc[i], 0, 0, 0);
            }
        }
    }

    #pragma unroll
    for (int i = 0; i < 3; ++i) {
        if (i == 2 && wv != 0) continue;
        int t = wv + 8 * i;
        int col = t * 16 + l15;
        float bj = (col < HH) ? bias[col] : 0.f;
        float y0 = acc[i][0] + bj, y1 = acc[i][1] + bj;
        float y2 = acc[i][2] + bj, y3 = acc[i][3] + bj;
        ylds[(quad*4 + 0) * YS + col] = y0;
        ylds[(quad*4 + 1) * YS + col] = y1;
        ylds[(quad*4 + 2) * YS + col] = y2;
        ylds[(quad*4 + 3) * YS + col] = y3;
        float sp = y0 + y1 + y2 + y3;
        float sq = y0*y0 + y1*y1 + y2*y2 + y3*y3;
        sp += __shfl_xor(sp, 16); sp += __shfl_xor(sp, 32);
        sq += __shfl_xor(sq, 16); sq += __shfl_xor(sq, 32);
        if (quad == 0 && col < HH) {
            float* spp = stats_out + (bid & 7) * 544;
            atomicAdd(spp + col, sp);
            atomicAdd(spp + 272 + col, sq);
        }
    }
}

// ---------------- phase: P3 grad GEMM + v/xc update + P1(s+1) GEMM --------------
__device__ __forceinline__ void dev_fused16(
    int bid,
    const float* __restrict__ y2l, const float* __restrict__ stats_in,
    const float* __restrict__ g2, const float* __restrict__ be2,
    const ushort_t* __restrict__ W3q, const float* __restrict__ b3,
    const float* __restrict__ law, const float* __restrict__ dWs,
    const float* __restrict__ tg, int s, int doP1,
    float* __restrict__ xcl, float* __restrict__ vv, float* __restrict__ outv,
    const ushort_t* __restrict__ W1q, const float* __restrict__ b1n,
    float* __restrict__ y1l, float* __restrict__ stats_out,
    float* __restrict__ zero_ptr,
    ushort_t* __restrict__ As, float (*AC)[HP], float* __restrict__ red)
{
    const int tid  = threadIdx.x;
    const int lane = tid & 63;
    const int wv   = tid >> 6;
    const int quad = lane >> 4;
    const int l15  = lane & 15;
    const int row0 = bid * 16;

    if (zero_ptr != nullptr && tid < 34)
        atomicExch(zero_ptr + bid * 34 + tid, 0.0f);

    compute_ac_coh(stats_in, g2, be2, AC);
    __syncthreads();

    // stage A2 = relu(affine(Y2)): 16 rows x 288 (K padded)
    for (int idx = tid; idx < 16 * 144; idx += 512) {
        int m  = idx / 144;
        int kk = (idx - m * 144) * 2;
        float v0 = (kk < HH)   ? fmaxf(fmaf(AC[0][kk],   y2l[m * YS + kk],   AC[1][kk]),   0.f) : 0.f;
        float v1 = (kk+1 < HH) ? fmaxf(fmaf(AC[0][kk+1], y2l[m * YS + kk+1], AC[1][kk+1]), 0.f) : 0.f;
        ((unsigned int*)As)[m * (AS_STRIDE/2) + (kk >> 1)] =
            (unsigned int)f2b(v0) | ((unsigned int)f2b(v1) << 16);
    }
    __syncthreads();

    // P3 GEMM: KT=9, NT=16, tiles t = wv, wv+8
    f32x4 acc[2];
    acc[0] = (f32x4){0.f,0.f,0.f,0.f};
    acc[1] = (f32x4){0.f,0.f,0.f,0.f};
    #pragma unroll 3
    for (int kt = 0; kt < 9; ++kt) {
        short8 af = *(const short8*)(&As[l15 * AS_STRIDE + kt * 32 + quad * 8]);
        const ushort_t* wp = W3q + ((size_t)(kt * 16 + wv)) * 512 + lane * 8;
        acc[0] = __builtin_amdgcn_mfma_f32_16x16x32_bf16(af, *(const short8*)(wp),           acc[0], 0, 0, 0);
        acc[1] = __builtin_amdgcn_mfma_f32_16x16x32_bf16(af, *(const short8*)(wp + 8 * 512), acc[1], 0, 0, 0);
    }

    // epilogue: grad, row partials (dW/law/b3 L2-warmed by P2's prefetch)
    const float h   = tg[s + 1] - tg[s];
    const float srt = SIG * sqrtf(h);
    float grad[2][4], xcv[2][4], dwv[2][4];
    float sxr[4], sgr[4], sgnr[4];
    #pragma unroll
    for (int i = 0; i < 2; ++i) {
        int col = (wv + 8*i) * 16 + l15;
        const float lawv = law[col];
        const float b3v  = b3[col];
        #pragma unroll
        for (int r = 0; r < 4; ++r) {
            int rl = quad * 4 + r;
            float gd = acc[i][r] + b3v;
            float xv = xcl[rl * XS + col];
            float dw = dWs[(size_t)(row0 + rl) * DD + col];
            float d  = xv - lawv;
            grad[i][r] = gd; xcv[i][r] = xv; dwv[i][r] = dw;
            if (i == 0) {
                sxr[r]  = d * d;
                sgr[r]  = gd * gd;
                sgnr[r] = gd * dw;
            } else {
                sxr[r]  = fmaf(d, d, sxr[r]);
                sgr[r]  = fmaf(gd, gd, sgr[r]);
                sgnr[r] = fmaf(gd, dw, sgnr[r]);
            }
        }
    }
    #pragma unroll
    for (int off = 1; off < 16; off <<= 1) {
        #pragma unroll
        for (int r = 0; r < 4; ++r) {
            sxr[r]  += __shfl_xor(sxr[r],  off);
            sgr[r]  += __shfl_xor(sgr[r],  off);
            sgnr[r] += __shfl_xor(sgnr[r], off);
        }
    }
    if (l15 == 0) {
        #pragma unroll
        for (int r = 0; r < 4; ++r) {
            int rr = quad * 4 + r;
            red[(wv * 16 + rr) * 3 + 0] = sxr[r];
            red[(wv * 16 + rr) * 3 + 1] = sgr[r];
            red[(wv * 16 + rr) * 3 + 2] = sgnr[r];
        }
    }
    __syncthreads();   // red ready; all waves done reading As (P3)

    if (tid < 16) {
        float sx = 0.f, sg = 0.f, sgn = 0.f;
        #pragma unroll
        for (int w = 0; w < 8; ++w) {
            sx  += red[(w * 16 + tid) * 3 + 0];
            sg  += red[(w * 16 + tid) * 3 + 1];
            sgn += red[(w * 16 + tid) * 3 + 2];
        }
        int row = row0 + tid;
        float f  = 0.5f * (sx + sg);
        float vn = vv[row] - f * h + srt * sgn;
        vv[row] = vn;
        if (s == SS - 1) outv[row] = vn;
    }

    // xc update (LDS) + stage new A1 into As (bf16)
    #pragma unroll
    for (int i = 0; i < 2; ++i) {
        int col = (wv + 8*i) * 16 + l15;
        #pragma unroll
        for (int r = 0; r < 4; ++r) {
            int rl = quad * 4 + r;
            float xn = xcv[i][r] - grad[i][r] * h + srt * dwv[i][r];
            xcl[rl * XS + col] = xn;
            if (doP1) As[rl * AS_STRIDE + col] = f2b(xn);
        }
    }
    if (!doP1) return;
    __syncthreads();

    // P1(s+1) GEMM: KT=8, NT=17
    f32x4 acc2[3];
    #pragma unroll
    for (int i = 0; i < 3; ++i) acc2[i] = (f32x4){0.f, 0.f, 0.f, 0.f};
    #pragma unroll 4
    for (int kt = 0; kt < 8; ++kt) {
        short8 af = *(const short8*)(&As[l15 * AS_STRIDE + kt * 32 + quad * 8]);
        const ushort_t* wp = W1q + ((size_t)(kt * 17 + wv)) * 512 + lane * 8;
        #pragma unroll
        for (int i = 0; i < 3; ++i) {
            if (i < 2 || wv == 0) {
                short8 bf = *(const short8*)(wp + (size_t)i * 8 * 512);
                acc2[i] = __builtin_amdgcn_mfma_f32_16x16x32_bf16(af, bf, acc2[i], 0, 0, 0);
            }
        }
    }
    #pragma unroll
    for (int i = 0; i < 3; ++i) {
        if (i == 2 && wv != 0) continue;
        int t = wv + 8 * i;
        int col = t * 16 + l15;
        float bj = (col < HH) ? b1n[col] : 0.f;
        float y0 = acc2[i][0] + bj, y1 = acc2[i][1] + bj;
        float y2 = acc2[i][2] + bj, y3 = acc2[i][3] + bj;
        y1l[(quad*4 + 0) * YS + col] = y0;
        y1l[(quad*4 + 1) * YS + col] = y1;
        y1l[(quad*4 + 2) * YS + col] = y2;
        y1l[(quad*4 + 3) * YS + col] = y3;
        float sp = y0 + y1 + y2 + y3;
        float sq = y0*y0 + y1*y1 + y2*y2 + y3*y3;
        sp += __shfl_xor(sp, 16); sp += __shfl_xor(sp, 32);
        sq += __shfl_xor(sq, 16); sq += __shfl_xor(sq, 32);
        if (quad == 0 && col < HH) {
            float* spp = stats_out + (bid & 7) * 544;
            atomicAdd(spp + col, sp);
            atomicAdd(spp + 272 + col, sq);
        }
    }
}

// ---------------- v0 layer 3 (N=1), 16 rows/block, 32 lanes/row ---------------
__device__ __forceinline__ void dev_v0l3_16(
    int bid, const float* __restrict__ y2l, const float* __restrict__ stats_in,
    const float* __restrict__ gv, const float* __restrict__ bev,
    const float* __restrict__ wv3, const float* __restrict__ bv3,
    float* __restrict__ vout, float* __restrict__ sv,
    float (*AC)[HP], float* __restrict__ xtra)
{
    const int tid = threadIdx.x;
    compute_ac_coh(stats_in, gv, bev, AC);
    __syncthreads();

    const int r  = tid >> 5;        // 0..15 (32 lanes per row)
    const int ks = tid & 31;
    int k0 = ks * 9, k1 = k0 + 9;
    if (k1 > HH) k1 = HH;
    float acc = 0.0f;
    for (int k = k0; k < k1; ++k) {
        float y  = y2l[r * YS + k];
        float a2 = fmaxf(fmaf(AC[0][k], y, AC[1][k]), 0.0f);
        acc = fmaf(a2, wv3[k], acc);
    }
    #pragma unroll
    for (int off = 1; off < 32; off <<= 1) acc += __shfl_xor(acc, off);
    if (ks == 0) {
        float y = acc + bv3[0];
        vout[bid * 16 + r] = y;
        xtra[r] = y;
        xtra[16 + r] = y * y;
    }
    __syncthreads();
    if (tid == 0) {
        float s = 0.f, q = 0.f;
        #pragma unroll
        for (int i = 0; i < 16; ++i) { s += xtra[i]; q += xtra[16 + i]; }
        atomicAdd(sv, s);
        atomicAdd(sv + 1, q);
    }
}

__device__ __forceinline__ void dev_v0fin16(int bid, float* __restrict__ v,
                                            const float* __restrict__ sv,
                                            const float* __restrict__ gv3,
                                            const float* __restrict__ bev3) {
    if (threadIdx.x < 16) {
        float s0 = ld_coh(sv);
        float s1 = ld_coh(sv + 1);
        float mu  = s0 * (1.0f / 2048.0f);
        float var = s1 * (1.0f / 2048.0f) - mu * mu;
        float rs  = rsqrtf(fmaxf(var, 0.0f) + BN_EPS);
        int row = bid * 16 + threadIdx.x;
        float y = v[row];
        v[row] = fmaxf(gv3[0] * (y - mu) * rs + bev3[0], 0.0f);
    }
}

// ---------------- the persistent kernel ----------------
__global__ __launch_bounds__(512) void k_persist(
    const float* __restrict__ x, const float* __restrict__ dW,
    const float* __restrict__ law, const float* __restrict__ tg,
    const float* __restrict__ b1, const float* __restrict__ g1, const float* __restrict__ be1,
    const float* __restrict__ b2, const float* __restrict__ g2, const float* __restrict__ be2,
    const float* __restrict__ b3,
    const float* __restrict__ bv1, const float* __restrict__ gv1, const float* __restrict__ bev1,
    const float* __restrict__ bv2, const float* __restrict__ gv2, const float* __restrict__ bev2,
    const float* __restrict__ Wv3, const float* __restrict__ bv3,
    const float* __restrict__ gv3, const float* __restrict__ bev3,
    float* __restrict__ ws, float* __restrict__ out)
{
    __shared__ ushort_t As[16 * AS_STRIDE];   //  9472 B
    __shared__ float AC[2][HP];               //  2176 B
    __shared__ float Y1s[16 * YS];            // 17664 B
    __shared__ float Y2s[16 * YS];            // 17664 B
    __shared__ float XCs[16 * XS];            // 16640 B
    __shared__ float XTRA[384];               //  1536 B   total 65152 B

    const int bid = blockIdx.x;
    const int tid = threadIdx.x;

    float* V   = ws + V_OFF;
    float* S1  = ws + S1_OFF;
    float* S2  = ws + S2_OFF;
    float* S1v = ws + S1V_OFF;
    float* S2v = ws + S2V_OFF;
    float* SV  = ws + SV_OFF;
    ushort_t* WQ = (ushort_t*)(ws + WQ_OFF);
    ushort_t* W1q  = WQ + W1Q_OFF;
    ushort_t* W2q  = WQ + W2Q_OFF;
    ushort_t* W3q  = WQ + W3Q_OFF;
    ushort_t* Wv1q = WQ + WV1Q_OFF;
    ushort_t* Wv2q = WQ + WV2Q_OFF;
    unsigned* bar  = (unsigned*)(ws + BAR_OFF);

    unsigned gen = 0;
    const int sl = (bid >> 3) & 15;   // weight-prefetch slice (16 per XCD group)

    // ph0: xc(LDS) = x rows; zero stat buffers (LLC RMW), spread across blocks.
    for (int i = tid; i < 16 * DD; i += 512) {
        int r = i >> 8, c = i & 255;
        XCs[r * XS + c] = x[(size_t)bid * 16 * DD + i];
    }
    {
        int z = bid * 205 + tid;
        int ze = (bid + 1) * 205; if (ze > 26128) ze = 26128;
        if (tid < 205 && z < ze) atomicExch(S1 + z, 0.0f);
    }
    grid_bar(bar, gen, bid); gen++;

    // ph1: v0 layer 1 (x @ Wv1) -> Y1s, stats -> S1v
    dev_lin16(bid, 0, 8, x, nullptr, nullptr, nullptr, nullptr,
              Wv1q, bv1, Y1s, S1v, nullptr, As, AC);
    grid_bar(bar, gen, bid); gen++;

    // ph2: v0 layer 2 (relu(bn(Y1)) @ Wv2) -> Y2s, stats -> S2v
    dev_lin16(bid, 2, 9, nullptr, Y1s, S1v, gv1, bev1,
              Wv2q, bv2, Y2s, S2v, nullptr, As, AC);
    grid_bar(bar, gen, bid); gen++;

    // ph3: v0 layer 3 (N=1) -> V, SV
    dev_v0l3_16(bid, Y2s, S2v, gv2, bev2, Wv3, bv3, V, SV, AC, XTRA);
    grid_bar(bar, gen, bid); gen++;

    // ph4: v0 final BN+relu on V + P1(0): x @ W1[0] -> Y1s, stats -> S1[0];
    //      batch-prefetch W2(0) slice
    dev_v0fin16(bid, V, SV, gv3, bev3);
    dev_lin16(bid, 0, 8, x, nullptr, nullptr, nullptr, nullptr,
              W1q, b1, Y1s, S1, nullptr, As, AC);
    {
        f32x4 p0, p1;
        pf2((const f32x4*)((const char*)W2q + (size_t)sl * 9792), 612, tid, p0, p1);
        asm volatile("" :: "v"(p0), "v"(p1));
    }
    grid_bar(bar, gen, bid); gen++;

    // main loop: 2 phases (2 barriers) per step
    for (int s = 0; s < SS; ++s) {
        int p = s & 1;
        // P2: relu(bn(Y1)) @ W2[s] -> Y2s, stats -> S2[p]; zero S1[1-p]
        dev_lin16(bid, 2, 9, nullptr, Y1s, S1 + p * 4352,
                  g1 + s * HH, be1 + s * HH,
                  W2q + (size_t)s * W2S, b2 + s * HH,
                  Y2s, S2 + p * 4352, S1 + (1 - p) * 4352, As, AC);
        // batch-prefetch F(s) inputs: own dW slice, W3(s)/W1(s+1) slices, law/b3
        {
            f32x4 d0, d1, w30, w31, w10, w11, lb;
            pf2((const f32x4*)(dW + (size_t)s * BATCH * DD + (size_t)bid * 16 * DD),
                1024, tid, d0, d1);
            pf2((const f32x4*)((const char*)(W3q + (size_t)s * W3S) + (size_t)sl * 9216),
                576, tid, w30, w31);
            int sn0 = (s + 1 < SS) ? s + 1 : s;
            pf2((const f32x4*)((const char*)(W1q + (size_t)sn0 * W1S) + (size_t)sl * 8704),
                544, tid, w10, w11);
            const f32x4* ql = (const f32x4*)(law + (size_t)s * DD);
            const f32x4* qb = (const f32x4*)(b3 + (size_t)s * DD);
            lb = (tid < 64) ? ql[tid] : ((tid < 128) ? qb[tid - 64] : ql[0]);
            asm volatile("" :: "v"(d0), "v"(d1), "v"(w30), "v"(w31),
                              "v"(w10), "v"(w11), "v"(lb));
        }
        grid_bar(bar, gen, bid); gen++;

        // F: P3 grad + v/xc update + P1(s+1) -> Y1s, stats -> S1[1-p]; zero S2[1-p]
        int sn = (s + 1 < SS) ? s + 1 : 0;   // dummy valid ptrs when doP1==0
        dev_fused16(bid, Y2s, S2 + p * 4352,
                    g2 + s * HH, be2 + s * HH,
                    W3q + (size_t)s * W3S, b3 + s * DD,
                    law + s * DD, dW + (size_t)s * BATCH * DD,
                    tg, s, (s < SS - 1) ? 1 : 0,
                    XCs, V, out,
                    W1q + (size_t)sn * W1S, b1 + sn * HH,
                    Y1s, S1 + ((s + 1) & 1) * 4352,
                    S2 + (1 - p) * 4352, As, AC, XTRA);
        // batch-prefetch W2(s+1) slice
        if (s + 1 < SS) {
            f32x4 p0, p1;
            pf2((const f32x4*)((const char*)(W2q + (size_t)(s + 1) * W2S) + (size_t)sl * 9792),
                612, tid, p0, p1);
            asm volatile("" :: "v"(p0), "v"(p1));
        }
        grid_bar(bar, gen, bid); gen++;
    }
}

extern "C" void kernel_launch(void* const* d_in, const int* in_sizes, int n_in,
                              void* d_out, int out_size, void* d_ws, size_t ws_size,
                              hipStream_t stream)
{
    (void)in_sizes; (void)n_in; (void)out_size; (void)ws_size;
    const float* x    = (const float*)d_in[0];
    const float* dW   = (const float*)d_in[1];
    const float* law  = (const float*)d_in[2];
    const float* tg   = (const float*)d_in[3];
    const float* W1   = (const float*)d_in[4];
    const float* b1   = (const float*)d_in[5];
    const float* g1   = (const float*)d_in[6];
    const float* be1  = (const float*)d_in[7];
    const float* W2   = (const float*)d_in[8];
    const float* b2   = (const float*)d_in[9];
    const float* g2   = (const float*)d_in[10];
    const float* be2  = (const float*)d_in[11];
    const float* W3   = (const float*)d_in[12];
    const float* b3   = (const float*)d_in[13];
    const float* Wv1  = (const float*)d_in[14];
    const float* bv1  = (const float*)d_in[15];
    const float* gv1  = (const float*)d_in[16];
    const float* bev1 = (const float*)d_in[17];
    const float* Wv2  = (const float*)d_in[18];
    const float* bv2  = (const float*)d_in[19];
    const float* gv2  = (const float*)d_in[20];
    const float* bev2 = (const float*)d_in[21];
    const float* Wv3  = (const float*)d_in[22];
    const float* bv3  = (const float*)d_in[23];
    const float* gv3  = (const float*)d_in[24];
    const float* bev3 = (const float*)d_in[25];

    float* ws = (float*)d_ws;
    ushort_t* WQ = (ushort_t*)(ws + WQ_OFF);
    ushort_t* W1q  = WQ + W1Q_OFF;
    ushort_t* W2q  = WQ + W2Q_OFF;
    ushort_t* W3q  = WQ + W3Q_OFF;
    ushort_t* Wv1q = WQ + WV1Q_OFF;
    ushort_t* Wv2q = WQ + WV2Q_OFF;
    float* out = (float*)d_out;

    k_pre<<<1, 256, 0, stream>>>(ws);
    // W1 (50 steps) + Wv1 folded as step 50
    k_conv_t<8, 17><<<dim3(272, 51), 256, 0, stream>>>(
        W1, W1q, DD, HH, SS, Wv1, Wv1q, DD, HH);
    // W2 (50 steps) + Wv2 folded as step 50
    k_conv_t<9, 17><<<dim3(306, 51), 256, 0, stream>>>(
        W2, W2q, HH, HH, SS, Wv2, Wv2q, HH, HH);
    // W3 (50 steps)
    k_conv_t<9, 16><<<dim3(288, 50), 256, 0, stream>>>(
        W3, W3q, HH, DD, SS, nullptr, nullptr, 0, 0);

    k_persist<<<128, 512, 0, stream>>>(
        x, dW, law, tg,
        b1, g1, be1, b2, g2, be2, b3,
        bv1, gv1, bev1, bv2, gv2, bev2,
        Wv3, bv3, gv3, bev3,
        ws, out);
}